// Round 1
// baseline (3909.352 us; speedup 1.0000x reference)
//
#include <hip/hip_runtime.h>
#include <math.h>

#define DM 1024
#define NH 16
#define DKK 64
#define BB 4
#define TT 2048
// 8192 total rows

// ---------------------------------------------------------------------------
// GEMM: C[m,n] = sum_k A[m,k] * W[n,k] + bias[n]
// A row-major [M=8192, K=1024], W row-major [N=1024, K=1024]
// QKV version: blockIdx.z selects (Wq,bq,Q)/(Wk,bk,K)/(Wv,bv,V),
// output scattered to [b, h, t, dk] layout.
// ---------------------------------------------------------------------------
__global__ __launch_bounds__(256) void qkv_gemm(
    const float* __restrict__ X,
    const float* __restrict__ Wq, const float* __restrict__ Wk, const float* __restrict__ Wv,
    const float* __restrict__ bq, const float* __restrict__ bk, const float* __restrict__ bv,
    float* __restrict__ Qo, float* __restrict__ Ko, float* __restrict__ Vo)
{
    const int wz = blockIdx.z;
    const float* Wp = (wz == 0) ? Wq : ((wz == 1) ? Wk : Wv);
    const float* bp = (wz == 0) ? bq : ((wz == 1) ? bk : bv);
    float* Op       = (wz == 0) ? Qo : ((wz == 1) ? Ko : Vo);

    __shared__ float As[64][36];
    __shared__ float Bs[64][36];

    const int tid = threadIdx.x;
    const int tx = tid & 15;
    const int ty = tid >> 4;
    const int m0 = blockIdx.x * 64;
    const int n0 = blockIdx.y * 64;

    float acc[4][4] = {};

    for (int k0 = 0; k0 < DM; k0 += 32) {
        #pragma unroll
        for (int l = 0; l < 2; ++l) {
            int f = tid + l * 256;       // float4 index within 64x32 tile
            int r = f >> 3;              // 8 float4 per row
            int c = (f & 7) << 2;
            *(float4*)&As[r][c] = *(const float4*)&X[(m0 + r) * DM + k0 + c];
            *(float4*)&Bs[r][c] = *(const float4*)&Wp[(n0 + r) * DM + k0 + c];
        }
        __syncthreads();
        #pragma unroll
        for (int k = 0; k < 32; k += 4) {
            float4 a[4], b[4];
            #pragma unroll
            for (int i = 0; i < 4; ++i) a[i] = *(const float4*)&As[ty * 4 + i][k];
            #pragma unroll
            for (int j = 0; j < 4; ++j) b[j] = *(const float4*)&Bs[tx * 4 + j][k];
            #pragma unroll
            for (int i = 0; i < 4; ++i)
                #pragma unroll
                for (int j = 0; j < 4; ++j)
                    acc[i][j] += a[i].x * b[j].x + a[i].y * b[j].y +
                                 a[i].z * b[j].z + a[i].w * b[j].w;
        }
        __syncthreads();
    }

    const float4 bb = *(const float4*)&bp[n0 + tx * 4];
    const int gn = n0 + tx * 4;
    const int h_ = gn >> 6;
    const int d_ = gn & 63;
    #pragma unroll
    for (int i = 0; i < 4; ++i) {
        int gm = m0 + ty * 4 + i;
        int b_ = gm >> 11;
        int t_ = gm & 2047;
        float4 o;
        o.x = acc[i][0] + bb.x;
        o.y = acc[i][1] + bb.y;
        o.z = acc[i][2] + bb.z;
        o.w = acc[i][3] + bb.w;
        *(float4*)&Op[(((b_ * NH + h_) * TT + t_) << 6) + d_] = o;
    }
}

// ---------------------------------------------------------------------------
// Output projection: out[m,n] = sum_k AO[m,k]*Wo[n,k] + bo[n], direct layout
// ---------------------------------------------------------------------------
__global__ __launch_bounds__(256) void out_gemm(
    const float* __restrict__ A, const float* __restrict__ W,
    const float* __restrict__ bias, float* __restrict__ out)
{
    __shared__ float As[64][36];
    __shared__ float Bs[64][36];

    const int tid = threadIdx.x;
    const int tx = tid & 15;
    const int ty = tid >> 4;
    const int m0 = blockIdx.x * 64;
    const int n0 = blockIdx.y * 64;

    float acc[4][4] = {};

    for (int k0 = 0; k0 < DM; k0 += 32) {
        #pragma unroll
        for (int l = 0; l < 2; ++l) {
            int f = tid + l * 256;
            int r = f >> 3;
            int c = (f & 7) << 2;
            *(float4*)&As[r][c] = *(const float4*)&A[(m0 + r) * DM + k0 + c];
            *(float4*)&Bs[r][c] = *(const float4*)&W[(n0 + r) * DM + k0 + c];
        }
        __syncthreads();
        #pragma unroll
        for (int k = 0; k < 32; k += 4) {
            float4 a[4], b[4];
            #pragma unroll
            for (int i = 0; i < 4; ++i) a[i] = *(const float4*)&As[ty * 4 + i][k];
            #pragma unroll
            for (int j = 0; j < 4; ++j) b[j] = *(const float4*)&Bs[tx * 4 + j][k];
            #pragma unroll
            for (int i = 0; i < 4; ++i)
                #pragma unroll
                for (int j = 0; j < 4; ++j)
                    acc[i][j] += a[i].x * b[j].x + a[i].y * b[j].y +
                                 a[i].z * b[j].z + a[i].w * b[j].w;
        }
        __syncthreads();
    }

    const float4 bb = *(const float4*)&bias[n0 + tx * 4];
    #pragma unroll
    for (int i = 0; i < 4; ++i) {
        int gm = m0 + ty * 4 + i;
        float4 o;
        o.x = acc[i][0] + bb.x;
        o.y = acc[i][1] + bb.y;
        o.z = acc[i][2] + bb.z;
        o.w = acc[i][3] + bb.w;
        *(float4*)&out[gm * DM + n0 + tx * 4] = o;
    }
}

// ---------------------------------------------------------------------------
// Flash-style attention. One workgroup per (b, h, 64-row q-tile).
// Q,K,V in [b,h,t,dk] fp32; output AO in [b,t,h*dk] layout.
// 256 threads as 16x16; each thread owns a 4x4 patch of the 64x64 S-tile
// and a 4x4 patch of the 64(rows)x64(dk) O accumulator.
// ---------------------------------------------------------------------------
__global__ __launch_bounds__(256) void attn_fwd(
    const float* __restrict__ Q, const float* __restrict__ K,
    const float* __restrict__ V, float* __restrict__ AO)
{
    __shared__ float Qs[64][68];
    __shared__ float Bs[64][68];   // K tile, then V tile (time-shared)
    __shared__ float Ps[64][68];

    const int tid = threadIdx.x;
    const int tx = tid & 15;
    const int ty = tid >> 4;
    const int q0 = blockIdx.x * 64;
    const int h  = blockIdx.y;
    const int b  = blockIdx.z;

    const float* Qb = Q + (size_t)((b * NH + h) * TT) * DKK;
    const float* Kb = K + (size_t)((b * NH + h) * TT) * DKK;
    const float* Vb = V + (size_t)((b * NH + h) * TT) * DKK;

    // load Q tile (64x64 floats = 1024 float4, 4 per thread)
    #pragma unroll
    for (int l = 0; l < 4; ++l) {
        int f = tid + l * 256;
        int r = f >> 4;              // 16 float4 per row
        int c = (f & 15) << 2;
        *(float4*)&Qs[r][c] = *(const float4*)&Qb[(q0 + r) * DKK + c];
    }

    float m_[4], l_[4], o_[4][4];
    #pragma unroll
    for (int i = 0; i < 4; ++i) {
        m_[i] = -INFINITY;
        l_[i] = 0.f;
        #pragma unroll
        for (int j = 0; j < 4; ++j) o_[i][j] = 0.f;
    }

    for (int kt = 0; kt < TT; kt += 64) {
        __syncthreads();   // prev iter's PV reads of Bs/Ps complete
        // load K tile
        #pragma unroll
        for (int l = 0; l < 4; ++l) {
            int f = tid + l * 256;
            int r = f >> 4;
            int c = (f & 15) << 2;
            *(float4*)&Bs[r][c] = *(const float4*)&Kb[(kt + r) * DKK + c];
        }
        __syncthreads();   // K tile ready (first iter: also Qs ready)

        // S = (Q K^T) * 0.125
        float s[4][4] = {};
        #pragma unroll
        for (int k = 0; k < 64; k += 4) {
            float4 a[4], c4[4];
            #pragma unroll
            for (int i = 0; i < 4; ++i) a[i]  = *(const float4*)&Qs[ty * 4 + i][k];
            #pragma unroll
            for (int j = 0; j < 4; ++j) c4[j] = *(const float4*)&Bs[tx * 4 + j][k];
            #pragma unroll
            for (int i = 0; i < 4; ++i)
                #pragma unroll
                for (int j = 0; j < 4; ++j)
                    s[i][j] += a[i].x * c4[j].x + a[i].y * c4[j].y +
                               a[i].z * c4[j].z + a[i].w * c4[j].w;
        }

        // online softmax update per row
        #pragma unroll
        for (int i = 0; i < 4; ++i) {
            #pragma unroll
            for (int j = 0; j < 4; ++j) s[i][j] *= 0.125f;
            float mx = fmaxf(fmaxf(s[i][0], s[i][1]), fmaxf(s[i][2], s[i][3]));
            #pragma unroll
            for (int mm = 1; mm < 16; mm <<= 1) mx = fmaxf(mx, __shfl_xor(mx, mm));
            float mnew = fmaxf(m_[i], mx);
            float scale = __expf(m_[i] - mnew);
            float sum = 0.f;
            #pragma unroll
            for (int j = 0; j < 4; ++j) {
                s[i][j] = __expf(s[i][j] - mnew);
                sum += s[i][j];
            }
            #pragma unroll
            for (int mm = 1; mm < 16; mm <<= 1) sum += __shfl_xor(sum, mm);
            l_[i] = l_[i] * scale + sum;
            m_[i] = mnew;
            #pragma unroll
            for (int j = 0; j < 4; ++j) o_[i][j] *= scale;
            float4 pw;
            pw.x = s[i][0]; pw.y = s[i][1]; pw.z = s[i][2]; pw.w = s[i][3];
            *(float4*)&Ps[ty * 4 + i][tx * 4] = pw;
        }
        __syncthreads();   // Ps written; all K reads done

        // load V tile into Bs
        #pragma unroll
        for (int l = 0; l < 4; ++l) {
            int f = tid + l * 256;
            int r = f >> 4;
            int c = (f & 15) << 2;
            *(float4*)&Bs[r][c] = *(const float4*)&Vb[(kt + r) * DKK + c];
        }
        __syncthreads();   // V + Ps ready

        // O += P @ V
        #pragma unroll
        for (int k = 0; k < 64; k += 4) {
            float4 pv[4], vv[4];
            #pragma unroll
            for (int i = 0; i < 4; ++i)  pv[i]  = *(const float4*)&Ps[ty * 4 + i][k];
            #pragma unroll
            for (int kk = 0; kk < 4; ++kk) vv[kk] = *(const float4*)&Bs[k + kk][tx * 4];
            #pragma unroll
            for (int i = 0; i < 4; ++i) {
                #pragma unroll
                for (int j = 0; j < 4; ++j) {
                    o_[i][j] += pv[i].x * ((const float*)&vv[0])[j]
                              + pv[i].y * ((const float*)&vv[1])[j]
                              + pv[i].z * ((const float*)&vv[2])[j]
                              + pv[i].w * ((const float*)&vv[3])[j];
                }
            }
        }
    }

    // finalize: divide by l, write to [b, t, h*dk]
    #pragma unroll
    for (int i = 0; i < 4; ++i) {
        float inv = 1.f / l_[i];
        int t_ = q0 + ty * 4 + i;
        float4 o;
        o.x = o_[i][0] * inv;
        o.y = o_[i][1] * inv;
        o.z = o_[i][2] * inv;
        o.w = o_[i][3] * inv;
        *(float4*)&AO[(size_t)(b * TT + t_) * DM + h * DKK + tx * 4] = o;
    }
}

// ---------------------------------------------------------------------------
extern "C" void kernel_launch(void* const* d_in, const int* in_sizes, int n_in,
                              void* d_out, int out_size, void* d_ws, size_t ws_size,
                              hipStream_t stream) {
    const float* x  = (const float*)d_in[0];
    const float* wq = (const float*)d_in[1];
    const float* bq = (const float*)d_in[2];
    const float* wk = (const float*)d_in[3];
    const float* bk = (const float*)d_in[4];
    const float* wv = (const float*)d_in[5];
    const float* bv = (const float*)d_in[6];
    const float* wo = (const float*)d_in[7];
    const float* bo = (const float*)d_in[8];

    float* ws = (float*)d_ws;
    const size_t mat = (size_t)BB * TT * DM;   // 8192*1024
    float* Qw = ws;
    float* Kw = Qw + mat;
    float* Vw = Kw + mat;
    float* AO = Vw + mat;

    dim3 blk(256);
    qkv_gemm<<<dim3(128, 16, 3), blk, 0, stream>>>(x, wq, wk, wv, bq, bk, bv, Qw, Kw, Vw);
    attn_fwd<<<dim3(32, 16, 4), blk, 0, stream>>>(Qw, Kw, Vw, AO);
    out_gemm<<<dim3(128, 16, 1), blk, 0, stream>>>(AO, wo, bo, (float*)d_out);
}

// Round 2
// 520.545 us; speedup vs baseline: 7.5101x; 7.5101x over previous
//
#include <hip/hip_runtime.h>
#include <math.h>

#define DM 1024
#define NH 16
#define DKK 64
#define BB 4
#define TT 2048

typedef __attribute__((ext_vector_type(8))) short short8;
typedef __attribute__((ext_vector_type(4))) float f32x4;
typedef __attribute__((ext_vector_type(4))) unsigned short us4;

typedef const __attribute__((address_space(1))) void gvoid;
typedef __attribute__((address_space(3))) void lvoid;
#define GLOAD16(g, l) __builtin_amdgcn_global_load_lds((gvoid*)(g), (lvoid*)(l), 16, 0, 0)

__device__ __forceinline__ unsigned short f2bf(float f) {
    union { float f; unsigned int u; } v; v.f = f;
    unsigned int r = v.u + 0x7fffu + ((v.u >> 16) & 1u);
    return (unsigned short)(r >> 16);
}

// ---------------------------------------------------------------------------
// fp32 -> bf16 conversion, 8 elems/thread
// ---------------------------------------------------------------------------
__global__ __launch_bounds__(256) void f32_to_bf16(const float* __restrict__ src,
                                                   unsigned short* __restrict__ dst, int n8) {
    int i = blockIdx.x * 256 + threadIdx.x;
    if (i >= n8) return;
    float4 a = ((const float4*)src)[i * 2];
    float4 b = ((const float4*)src)[i * 2 + 1];
    us4 lo, hi;
    lo[0] = f2bf(a.x); lo[1] = f2bf(a.y); lo[2] = f2bf(a.z); lo[3] = f2bf(a.w);
    hi[0] = f2bf(b.x); hi[1] = f2bf(b.y); hi[2] = f2bf(b.z); hi[3] = f2bf(b.w);
    *(us4*)&dst[i * 8]     = lo;
    *(us4*)&dst[i * 8 + 4] = hi;
}

// ---------------------------------------------------------------------------
// Shared GEMM core: C(128x128) = A[m0:m0+128, :] @ B[n0rel:n0rel+128, :]^T
// A,B bf16 row-major with K=1024 contiguous. m97 structure: BK=32,
// global_load_lds 16B, 2 barriers/K-step, 4 waves (2x2), 4x4 16x16x32 MFMA.
// ---------------------------------------------------------------------------
__device__ __forceinline__ void gemm_core(const unsigned short* __restrict__ A,
                                          const unsigned short* __restrict__ Bm,
                                          int m0, int n0rel, f32x4 acc[4][4],
                                          unsigned short* As, unsigned short* Bs,
                                          int tid) {
    const int wv_ = tid >> 6, ln = tid & 63;
    const int wr = wv_ >> 1, wc = wv_ & 1;
    const int srow = tid >> 2;
    const int scol = (tid & 3) * 8;

    for (int k0 = 0; k0 < DM; k0 += 32) {
        #pragma unroll
        for (int l = 0; l < 2; ++l) {
            int row = l * 64 + srow;
            GLOAD16(&A[(size_t)(m0 + row) * DM + k0 + scol],  As + (l * 256 + wv_ * 64) * 8);
            GLOAD16(&Bm[(size_t)(n0rel + row) * DM + k0 + scol], Bs + (l * 256 + wv_ * 64) * 8);
        }
        __syncthreads();
        short8 af[4], bf_[4];
        #pragma unroll
        for (int mi = 0; mi < 4; ++mi)
            af[mi] = *(const short8*)&As[(wr * 64 + mi * 16 + (ln & 15)) * 32 + (ln >> 4) * 8];
        #pragma unroll
        for (int ni = 0; ni < 4; ++ni)
            bf_[ni] = *(const short8*)&Bs[(wc * 64 + ni * 16 + (ln & 15)) * 32 + (ln >> 4) * 8];
        #pragma unroll
        for (int mi = 0; mi < 4; ++mi)
            #pragma unroll
            for (int ni = 0; ni < 4; ++ni)
                acc[mi][ni] = __builtin_amdgcn_mfma_f32_16x16x32_bf16(af[mi], bf_[ni], acc[mi][ni], 0, 0, 0);
        __syncthreads();
    }
}

// ---------------------------------------------------------------------------
// Fused QKV projection. N = 3072 (wq|wk|wv); each 128-col block lies in one
// section. Q,K written [b,h,t,dk] bf16; V written transposed [b,h,dk,t] bf16.
// ---------------------------------------------------------------------------
__global__ __launch_bounds__(256) void qkv_gemm_bf16(
    const unsigned short* __restrict__ Xb,
    const unsigned short* __restrict__ Wqb, const unsigned short* __restrict__ Wkb,
    const unsigned short* __restrict__ Wvb,
    const float* __restrict__ bq, const float* __restrict__ bk, const float* __restrict__ bv,
    unsigned short* __restrict__ Qb, unsigned short* __restrict__ Kb, unsigned short* __restrict__ Vt)
{
    __shared__ unsigned short As[128 * 32];
    __shared__ unsigned short Bs[128 * 32];
    const int tid = threadIdx.x;
    const int m0 = blockIdx.x * 128;
    const int n0 = blockIdx.y * 128;
    const int sec = n0 >> 10;
    const unsigned short* Wsel = (sec == 0) ? Wqb : ((sec == 1) ? Wkb : Wvb);
    const float* bsel          = (sec == 0) ? bq  : ((sec == 1) ? bk  : bv);
    const int n0rel = n0 & 1023;

    f32x4 acc[4][4];
    #pragma unroll
    for (int i = 0; i < 4; ++i)
        #pragma unroll
        for (int j = 0; j < 4; ++j) acc[i][j] = (f32x4)0.f;

    gemm_core(Xb, Wsel, m0, n0rel, acc, As, Bs, tid);

    const int wv_ = tid >> 6, ln = tid & 63;
    const int wr = wv_ >> 1, wc = wv_ & 1;
    const int g = ln >> 4, c = ln & 15;
    const int b = m0 >> 11;                    // block fully within one batch
    const int t_base = (m0 & 2047) + wr * 64;

    #pragma unroll
    for (int ni = 0; ni < 4; ++ni) {
        int n = n0rel + wc * 64 + ni * 16 + c;
        float bia = bsel[n];
        int h = n >> 6, d = n & 63;
        #pragma unroll
        for (int mi = 0; mi < 4; ++mi) {
            int t0 = t_base + mi * 16 + g * 4;
            if (sec < 2) {
                unsigned short* Op = (sec == 0) ? Qb : Kb;
                size_t base = ((size_t)((b * NH + h) * TT) + t0) * DKK + d;
                #pragma unroll
                for (int j = 0; j < 4; ++j)
                    Op[base + (size_t)j * DKK] = f2bf(acc[mi][ni][j] + bia);
            } else {
                us4 pk;
                #pragma unroll
                for (int j = 0; j < 4; ++j) pk[j] = f2bf(acc[mi][ni][j] + bia);
                *(us4*)&Vt[((size_t)((b * NH + h) * DKK) + d) * TT + t0] = pk;
            }
        }
    }
}

// ---------------------------------------------------------------------------
// Output projection: fp32 out = AO @ Wo^T + bo
// ---------------------------------------------------------------------------
__global__ __launch_bounds__(256) void out_gemm_bf16(
    const unsigned short* __restrict__ Ab, const unsigned short* __restrict__ Wob,
    const float* __restrict__ bo, float* __restrict__ out)
{
    __shared__ unsigned short As[128 * 32];
    __shared__ unsigned short Bs[128 * 32];
    const int tid = threadIdx.x;
    const int m0 = blockIdx.x * 128;
    const int n0 = blockIdx.y * 128;

    f32x4 acc[4][4];
    #pragma unroll
    for (int i = 0; i < 4; ++i)
        #pragma unroll
        for (int j = 0; j < 4; ++j) acc[i][j] = (f32x4)0.f;

    gemm_core(Ab, Wob, m0, n0, acc, As, Bs, tid);

    const int wv_ = tid >> 6, ln = tid & 63;
    const int wr = wv_ >> 1, wc = wv_ & 1;
    const int g = ln >> 4, c = ln & 15;

    #pragma unroll
    for (int ni = 0; ni < 4; ++ni) {
        int n = n0 + wc * 64 + ni * 16 + c;
        float bia = bo[n];
        #pragma unroll
        for (int mi = 0; mi < 4; ++mi) {
            int r0 = m0 + wr * 64 + mi * 16 + g * 4;
            #pragma unroll
            for (int j = 0; j < 4; ++j)
                out[(size_t)(r0 + j) * DM + n] = acc[mi][ni][j] + bia;
        }
    }
}

// ---------------------------------------------------------------------------
// MFMA flash attention. Grid (T/128, B*H). 4 independent waves/block,
// 32 q-rows each; no __syncthreads. K,V read direct from global (L2/L3-fit).
// P transposed per-wave via private LDS (row stride 72 bf16 -> conflict-free).
// ---------------------------------------------------------------------------
__global__ __launch_bounds__(256) void attn_mfma(
    const unsigned short* __restrict__ Qg, const unsigned short* __restrict__ Kg,
    const unsigned short* __restrict__ Vtg, unsigned short* __restrict__ AOb)
{
    __shared__ unsigned short Ps[4][32][72];
    const int tid = threadIdx.x, wv_ = tid >> 6, ln = tid & 63;
    const int g = ln >> 4, c = ln & 15;
    const int q0 = blockIdx.x * 128;
    const int bh = blockIdx.y;
    const unsigned short* Qb = Qg  + (size_t)bh * TT * DKK;
    const unsigned short* Kb = Kg  + (size_t)bh * TT * DKK;
    const unsigned short* Vb = Vtg + (size_t)bh * DKK * TT;

    const int qbase = q0 + wv_ * 32;
    short8 qa[2][2];
    #pragma unroll
    for (int mi = 0; mi < 2; ++mi)
        #pragma unroll
        for (int kf = 0; kf < 2; ++kf)
            qa[mi][kf] = *(const short8*)&Qb[(size_t)(qbase + mi * 16 + c) * DKK + kf * 32 + g * 8];

    f32x4 o[2][4];
    float m_[2][4], l_[2][4];
    #pragma unroll
    for (int mi = 0; mi < 2; ++mi)
        #pragma unroll
        for (int j = 0; j < 4; ++j) {
            m_[mi][j] = -1e30f; l_[mi][j] = 0.f;
            if (j < 4) {}
        }
    #pragma unroll
    for (int mi = 0; mi < 2; ++mi)
        #pragma unroll
        for (int oj = 0; oj < 4; ++oj) o[mi][oj] = (f32x4)0.f;

    for (int kt = 0; kt < TT; kt += 64) {
        // ---- S = Q @ K^T over this 64-key block
        f32x4 s[2][4];
        #pragma unroll
        for (int mi = 0; mi < 2; ++mi)
            #pragma unroll
            for (int ni = 0; ni < 4; ++ni) s[mi][ni] = (f32x4)0.f;
        #pragma unroll
        for (int ni = 0; ni < 4; ++ni) {
            #pragma unroll
            for (int kf = 0; kf < 2; ++kf) {
                short8 kb = *(const short8*)&Kb[(size_t)(kt + ni * 16 + c) * DKK + kf * 32 + g * 8];
                #pragma unroll
                for (int mi = 0; mi < 2; ++mi)
                    s[mi][ni] = __builtin_amdgcn_mfma_f32_16x16x32_bf16(qa[mi][kf], kb, s[mi][ni], 0, 0, 0);
            }
        }
        // ---- online softmax (rows live across 16-lane groups; cols = ni,c)
        #pragma unroll
        for (int mi = 0; mi < 2; ++mi) {
            #pragma unroll
            for (int j = 0; j < 4; ++j) {
                float sv[4];
                #pragma unroll
                for (int ni = 0; ni < 4; ++ni) sv[ni] = s[mi][ni][j] * 0.125f;
                float mx = fmaxf(fmaxf(sv[0], sv[1]), fmaxf(sv[2], sv[3]));
                #pragma unroll
                for (int xm = 1; xm < 16; xm <<= 1) mx = fmaxf(mx, __shfl_xor(mx, xm));
                float mnew = fmaxf(m_[mi][j], mx);
                float sc = __expf(m_[mi][j] - mnew);
                float rs = 0.f;
                #pragma unroll
                for (int ni = 0; ni < 4; ++ni) { sv[ni] = __expf(sv[ni] - mnew); rs += sv[ni]; }
                #pragma unroll
                for (int xm = 1; xm < 16; xm <<= 1) rs += __shfl_xor(rs, xm);
                m_[mi][j] = mnew;
                l_[mi][j] = l_[mi][j] * sc + rs;
                #pragma unroll
                for (int oj = 0; oj < 4; ++oj) o[mi][oj][j] *= sc;
                #pragma unroll
                for (int ni = 0; ni < 4; ++ni)
                    Ps[wv_][mi * 16 + g * 4 + j][ni * 16 + c] = f2bf(sv[ni]);
            }
        }
        // ---- O += P @ V  (P from wave-private LDS, V^T from global)
        #pragma unroll
        for (int kf = 0; kf < 2; ++kf) {
            short8 pa[2];
            #pragma unroll
            for (int mi = 0; mi < 2; ++mi)
                pa[mi] = *(const short8*)&Ps[wv_][mi * 16 + c][kf * 32 + g * 8];
            #pragma unroll
            for (int oj = 0; oj < 4; ++oj) {
                short8 vb = *(const short8*)&Vb[(size_t)(oj * 16 + c) * TT + kt + kf * 32 + g * 8];
                #pragma unroll
                for (int mi = 0; mi < 2; ++mi)
                    o[mi][oj] = __builtin_amdgcn_mfma_f32_16x16x32_bf16(pa[mi], vb, o[mi][oj], 0, 0, 0);
            }
        }
    }

    // ---- finalize: /l, write AO [b, t, h*64+d] bf16
    const int b = bh >> 4, h = bh & 15;
    #pragma unroll
    for (int mi = 0; mi < 2; ++mi)
        #pragma unroll
        for (int j = 0; j < 4; ++j) {
            float inv = 1.0f / l_[mi][j];
            int t = qbase + mi * 16 + g * 4 + j;
            #pragma unroll
            for (int oj = 0; oj < 4; ++oj) {
                int d = oj * 16 + c;
                AOb[(size_t)(b * TT + t) * DM + h * DKK + d] = f2bf(o[mi][oj][j] * inv);
            }
        }
}

// ---------------------------------------------------------------------------
extern "C" void kernel_launch(void* const* d_in, const int* in_sizes, int n_in,
                              void* d_out, int out_size, void* d_ws, size_t ws_size,
                              hipStream_t stream) {
    const float* x  = (const float*)d_in[0];
    const float* wq = (const float*)d_in[1];
    const float* bq = (const float*)d_in[2];
    const float* wk = (const float*)d_in[3];
    const float* bk = (const float*)d_in[4];
    const float* wv = (const float*)d_in[5];
    const float* bv = (const float*)d_in[6];
    const float* wo = (const float*)d_in[7];
    const float* bo = (const float*)d_in[8];

    unsigned short* ws = (unsigned short*)d_ws;
    const size_t NX = (size_t)BB * TT * DM;      // 8388608
    const size_t NW = (size_t)DM * DM;           // 1048576
    unsigned short* xb  = ws;
    unsigned short* wqb = xb + NX;
    unsigned short* wkb = wqb + NW;
    unsigned short* wvb = wkb + NW;
    unsigned short* wob = wvb + NW;
    unsigned short* Qb  = wob + NW;
    unsigned short* Kb  = Qb + NX;
    unsigned short* Vt  = Kb + NX;
    unsigned short* AOb = Vt + NX;

    dim3 blk(256);
    f32_to_bf16<<<dim3((int)(NX / 8 / 256)), blk, 0, stream>>>(x,  xb,  (int)(NX / 8));
    f32_to_bf16<<<dim3((int)(NW / 8 / 256)), blk, 0, stream>>>(wq, wqb, (int)(NW / 8));
    f32_to_bf16<<<dim3((int)(NW / 8 / 256)), blk, 0, stream>>>(wk, wkb, (int)(NW / 8));
    f32_to_bf16<<<dim3((int)(NW / 8 / 256)), blk, 0, stream>>>(wv, wvb, (int)(NW / 8));
    f32_to_bf16<<<dim3((int)(NW / 8 / 256)), blk, 0, stream>>>(wo, wob, (int)(NW / 8));

    qkv_gemm_bf16<<<dim3(64, 24), blk, 0, stream>>>(xb, wqb, wkb, wvb, bq, bk, bv, Qb, Kb, Vt);
    attn_mfma<<<dim3(16, 64), blk, 0, stream>>>(Qb, Kb, Vt, AOb);
    out_gemm_bf16<<<dim3(64, 8), blk, 0, stream>>>(AOb, wob, bo, (float*)d_out);
}

// Round 3
// 321.942 us; speedup vs baseline: 12.1430x; 1.6169x over previous
//
#include <hip/hip_runtime.h>
#include <math.h>

#define DM 1024
#define NH 16
#define DKK 64
#define BB 4
#define TT 2048
#define KVB 64

typedef __attribute__((ext_vector_type(8))) short short8;
typedef __attribute__((ext_vector_type(4))) float f32x4;
typedef __attribute__((ext_vector_type(4))) unsigned short us4;

typedef const __attribute__((address_space(1))) void gvoid;
typedef __attribute__((address_space(3))) void lvoid;
#define GLOAD16(g, l) __builtin_amdgcn_global_load_lds((gvoid*)(g), (lvoid*)(l), 16, 0, 0)

__device__ __forceinline__ unsigned short f2bf(float f) {
    union { float f; unsigned int u; } v; v.f = f;
    unsigned int r = v.u + 0x7fffu + ((v.u >> 16) & 1u);
    return (unsigned short)(r >> 16);
}

// ---------------------------------------------------------------------------
// fp32 -> bf16 conversion, 8 elems/thread
// ---------------------------------------------------------------------------
__global__ __launch_bounds__(256) void f32_to_bf16(const float* __restrict__ src,
                                                   unsigned short* __restrict__ dst, int n8) {
    int i = blockIdx.x * 256 + threadIdx.x;
    if (i >= n8) return;
    float4 a = ((const float4*)src)[i * 2];
    float4 b = ((const float4*)src)[i * 2 + 1];
    us4 lo, hi;
    lo[0] = f2bf(a.x); lo[1] = f2bf(a.y); lo[2] = f2bf(a.z); lo[3] = f2bf(a.w);
    hi[0] = f2bf(b.x); hi[1] = f2bf(b.y); hi[2] = f2bf(b.z); hi[3] = f2bf(b.w);
    *(us4*)&dst[i * 8]     = lo;
    *(us4*)&dst[i * 8 + 4] = hi;
}

// ---------------------------------------------------------------------------
// Shared GEMM core (m97 structure): C(128x128) = A @ B^T, K=1024
// ---------------------------------------------------------------------------
__device__ __forceinline__ void gemm_core(const unsigned short* __restrict__ A,
                                          const unsigned short* __restrict__ Bm,
                                          int m0, int n0rel, f32x4 acc[4][4],
                                          unsigned short* As, unsigned short* Bs,
                                          int tid) {
    const int wv_ = tid >> 6, ln = tid & 63;
    const int wr = wv_ >> 1, wc = wv_ & 1;
    const int srow = tid >> 2;
    const int scol = (tid & 3) * 8;

    for (int k0 = 0; k0 < DM; k0 += 32) {
        #pragma unroll
        for (int l = 0; l < 2; ++l) {
            int row = l * 64 + srow;
            GLOAD16(&A[(size_t)(m0 + row) * DM + k0 + scol],  As + (l * 256 + wv_ * 64) * 8);
            GLOAD16(&Bm[(size_t)(n0rel + row) * DM + k0 + scol], Bs + (l * 256 + wv_ * 64) * 8);
        }
        __syncthreads();
        short8 af[4], bf_[4];
        #pragma unroll
        for (int mi = 0; mi < 4; ++mi)
            af[mi] = *(const short8*)&As[(wr * 64 + mi * 16 + (ln & 15)) * 32 + (ln >> 4) * 8];
        #pragma unroll
        for (int ni = 0; ni < 4; ++ni)
            bf_[ni] = *(const short8*)&Bs[(wc * 64 + ni * 16 + (ln & 15)) * 32 + (ln >> 4) * 8];
        #pragma unroll
        for (int mi = 0; mi < 4; ++mi)
            #pragma unroll
            for (int ni = 0; ni < 4; ++ni)
                acc[mi][ni] = __builtin_amdgcn_mfma_f32_16x16x32_bf16(af[mi], bf_[ni], acc[mi][ni], 0, 0, 0);
        __syncthreads();
    }
}

// ---------------------------------------------------------------------------
// Fused QKV projection. Q is pre-scaled by 0.125*log2(e) so attention softmax
// can run in the exp2 domain. Q,K -> [b,h,t,dk]; V -> transposed [b,h,dk,t].
// ---------------------------------------------------------------------------
__global__ __launch_bounds__(256) void qkv_gemm_bf16(
    const unsigned short* __restrict__ Xb,
    const unsigned short* __restrict__ Wqb, const unsigned short* __restrict__ Wkb,
    const unsigned short* __restrict__ Wvb,
    const float* __restrict__ bq, const float* __restrict__ bk, const float* __restrict__ bv,
    unsigned short* __restrict__ Qb, unsigned short* __restrict__ Kb, unsigned short* __restrict__ Vt)
{
    __shared__ unsigned short As[128 * 32];
    __shared__ unsigned short Bs[128 * 32];
    const int tid = threadIdx.x;
    const int m0 = blockIdx.x * 128;
    const int n0 = blockIdx.y * 128;
    const int sec = n0 >> 10;
    const unsigned short* Wsel = (sec == 0) ? Wqb : ((sec == 1) ? Wkb : Wvb);
    const float* bsel          = (sec == 0) ? bq  : ((sec == 1) ? bk  : bv);
    const int n0rel = n0 & 1023;

    f32x4 acc[4][4];
    #pragma unroll
    for (int i = 0; i < 4; ++i)
        #pragma unroll
        for (int j = 0; j < 4; ++j) acc[i][j] = (f32x4)0.f;

    gemm_core(Xb, Wsel, m0, n0rel, acc, As, Bs, tid);

    const int wv_ = tid >> 6, ln = tid & 63;
    const int wr = wv_ >> 1, wc = wv_ & 1;
    const int g = ln >> 4, c = ln & 15;
    const int b = m0 >> 11;
    const int t_base = (m0 & 2047) + wr * 64;
    const float scl = (sec == 0) ? 0.18033688011112042f : 1.0f;  // 0.125*log2(e)

    #pragma unroll
    for (int ni = 0; ni < 4; ++ni) {
        int n = n0rel + wc * 64 + ni * 16 + c;
        float bia = bsel[n];
        int h = n >> 6, d = n & 63;
        #pragma unroll
        for (int mi = 0; mi < 4; ++mi) {
            int t0 = t_base + mi * 16 + g * 4;
            if (sec < 2) {
                unsigned short* Op = (sec == 0) ? Qb : Kb;
                size_t base = ((size_t)((b * NH + h) * TT) + t0) * DKK + d;
                #pragma unroll
                for (int j = 0; j < 4; ++j)
                    Op[base + (size_t)j * DKK] = f2bf((acc[mi][ni][j] + bia) * scl);
            } else {
                us4 pk;
                #pragma unroll
                for (int j = 0; j < 4; ++j) pk[j] = f2bf(acc[mi][ni][j] + bia);
                *(us4*)&Vt[((size_t)((b * NH + h) * DKK) + d) * TT + t0] = pk;
            }
        }
    }
}

// ---------------------------------------------------------------------------
// Output projection: fp32 out = AO @ Wo^T + bo
// ---------------------------------------------------------------------------
__global__ __launch_bounds__(256) void out_gemm_bf16(
    const unsigned short* __restrict__ Ab, const unsigned short* __restrict__ Wob,
    const float* __restrict__ bo, float* __restrict__ out)
{
    __shared__ unsigned short As[128 * 32];
    __shared__ unsigned short Bs[128 * 32];
    const int tid = threadIdx.x;
    const int m0 = blockIdx.x * 128;
    const int n0 = blockIdx.y * 128;

    f32x4 acc[4][4];
    #pragma unroll
    for (int i = 0; i < 4; ++i)
        #pragma unroll
        for (int j = 0; j < 4; ++j) acc[i][j] = (f32x4)0.f;

    gemm_core(Ab, Wob, m0, n0, acc, As, Bs, tid);

    const int wv_ = tid >> 6, ln = tid & 63;
    const int wr = wv_ >> 1, wc = wv_ & 1;
    const int g = ln >> 4, c = ln & 15;

    #pragma unroll
    for (int ni = 0; ni < 4; ++ni) {
        int n = n0 + wc * 64 + ni * 16 + c;
        float bia = bo[n];
        #pragma unroll
        for (int mi = 0; mi < 4; ++mi) {
            int r0 = m0 + wr * 64 + mi * 16 + g * 4;
            #pragma unroll
            for (int j = 0; j < 4; ++j)
                out[(size_t)(r0 + j) * DM + n] = acc[mi][ni][j] + bia;
        }
    }
}

// ---------------------------------------------------------------------------
// MFMA flash attention, 2-phase prefetch schedule.
// K and V^T tiles staged in LDS via global_load_lds (linear dest, inverse-XOR-
// swizzled global source; reads apply the same XOR -> conflict-free b128).
// One __syncthreads (vmcnt drain) per 64-key tile. Softmax in exp2 domain
// (Q pre-scaled). P stays wave-private in LDS (no cross-wave barrier).
// ---------------------------------------------------------------------------
__global__ __launch_bounds__(256, 3) void attn_mfma(
    const unsigned short* __restrict__ Qg, const unsigned short* __restrict__ Kg,
    const unsigned short* __restrict__ Vtg, unsigned short* __restrict__ AOb)
{
    __shared__ unsigned short Ks[2][64 * 64];
    __shared__ unsigned short Vs[2][64 * 64];
    __shared__ unsigned short Ps[4][32][72];

    const int tid = threadIdx.x, wv_ = tid >> 6, ln = tid & 63;
    const int g = ln >> 4, c = ln & 15;

    // bijective XCD-clustering remap: all 16 q-blocks of one bh share orig%8
    const int orig = blockIdx.y * 16 + blockIdx.x;
    const int r8 = orig & 7, i8 = orig >> 3;
    const int bh = r8 * 8 + (i8 >> 4);
    const int q0 = (i8 & 15) * 128;

    const unsigned short* Qb = Qg  + (size_t)bh * TT * DKK;
    const unsigned short* Kb = Kg  + (size_t)bh * TT * DKK;
    const unsigned short* Vb = Vtg + (size_t)bh * DKK * TT;

    // Q fragments (already scaled by 0.125*log2e)
    const int qbase = q0 + wv_ * 32;
    short8 qa[2][2];
    #pragma unroll
    for (int mi = 0; mi < 2; ++mi)
        #pragma unroll
        for (int kf = 0; kf < 2; ++kf)
            qa[mi][kf] = *(const short8*)&Qb[(size_t)(qbase + mi * 16 + c) * DKK + kf * 32 + g * 8];

    // staging constants: 16B unit L = i*256+tid -> row r=L>>3, unit u=L&7;
    // source column-unit = u ^ (r&7) (inverse swizzle), dest linear.
    const int r0 = tid >> 3,         u0s = ((tid & 7) ^ (r0 & 7)) * 8;
    const int r1 = (256 + tid) >> 3, u1s = (((256 + tid) & 7) ^ (r1 & 7)) * 8;

#define STAGE(bufi, ktt) do {                                                          \
    GLOAD16(Kb + (size_t)((ktt) + r0) * DKK + u0s, &Ks[bufi][(wv_ * 64) * 8]);         \
    GLOAD16(Kb + (size_t)((ktt) + r1) * DKK + u1s, &Ks[bufi][(256 + wv_ * 64) * 8]);   \
    GLOAD16(Vb + (size_t)r0 * TT + (ktt) + u0s,    &Vs[bufi][(wv_ * 64) * 8]);         \
    GLOAD16(Vb + (size_t)r1 * TT + (ktt) + u1s,    &Vs[bufi][(256 + wv_ * 64) * 8]);   \
} while (0)

    f32x4 o[2][4];
    float m_[2][4], l_[2][4];
    #pragma unroll
    for (int mi = 0; mi < 2; ++mi)
        #pragma unroll
        for (int j = 0; j < 4; ++j) { m_[mi][j] = -1e30f; l_[mi][j] = 0.f; }
    #pragma unroll
    for (int mi = 0; mi < 2; ++mi)
        #pragma unroll
        for (int oj = 0; oj < 4; ++oj) o[mi][oj] = (f32x4)0.f;

    STAGE(0, 0);
    __syncthreads();

    int cur = 0;
    for (int kt = 0; kt < TT; kt += KVB) {
        if (kt + KVB < TT) STAGE(cur ^ 1, kt + KVB);

        // ---- S = Q K^T (exp2 domain), K from swizzled LDS
        f32x4 s[2][4];
        #pragma unroll
        for (int mi = 0; mi < 2; ++mi)
            #pragma unroll
            for (int ni = 0; ni < 4; ++ni) s[mi][ni] = (f32x4)0.f;
        __builtin_amdgcn_s_setprio(1);
        #pragma unroll
        for (int ni = 0; ni < 4; ++ni) {
            const int krow = ni * 16 + c;
            #pragma unroll
            for (int kf = 0; kf < 2; ++kf) {
                short8 kbf = *(const short8*)&Ks[cur][krow * 64 + ((4 * kf + g) ^ (c & 7)) * 8];
                #pragma unroll
                for (int mi = 0; mi < 2; ++mi)
                    s[mi][ni] = __builtin_amdgcn_mfma_f32_16x16x32_bf16(qa[mi][kf], kbf, s[mi][ni], 0, 0, 0);
            }
        }
        __builtin_amdgcn_s_setprio(0);

        // ---- online softmax (exp2 domain)
        #pragma unroll
        for (int mi = 0; mi < 2; ++mi) {
            #pragma unroll
            for (int j = 0; j < 4; ++j) {
                float sv[4];
                #pragma unroll
                for (int ni = 0; ni < 4; ++ni) sv[ni] = s[mi][ni][j];
                float mx = fmaxf(fmaxf(sv[0], sv[1]), fmaxf(sv[2], sv[3]));
                #pragma unroll
                for (int xm = 1; xm < 16; xm <<= 1) mx = fmaxf(mx, __shfl_xor(mx, xm));
                float mnew = fmaxf(m_[mi][j], mx);
                float sc = __builtin_amdgcn_exp2f(m_[mi][j] - mnew);
                float rs = 0.f;
                #pragma unroll
                for (int ni = 0; ni < 4; ++ni) {
                    sv[ni] = __builtin_amdgcn_exp2f(sv[ni] - mnew);
                    rs += sv[ni];
                }
                #pragma unroll
                for (int xm = 1; xm < 16; xm <<= 1) rs += __shfl_xor(rs, xm);
                m_[mi][j] = mnew;
                l_[mi][j] = l_[mi][j] * sc + rs;
                #pragma unroll
                for (int oj = 0; oj < 4; ++oj) o[mi][oj][j] *= sc;
                #pragma unroll
                for (int ni = 0; ni < 4; ++ni)
                    Ps[wv_][mi * 16 + g * 4 + j][ni * 16 + c] = f2bf(sv[ni]);
            }
        }

        // ---- O += P @ V, V^T from swizzled LDS, P wave-private
        __builtin_amdgcn_s_setprio(1);
        #pragma unroll
        for (int kf = 0; kf < 2; ++kf) {
            short8 pa[2];
            #pragma unroll
            for (int mi = 0; mi < 2; ++mi)
                pa[mi] = *(const short8*)&Ps[wv_][mi * 16 + c][kf * 32 + g * 8];
            #pragma unroll
            for (int oj = 0; oj < 4; ++oj) {
                short8 vbf = *(const short8*)&Vs[cur][(oj * 16 + c) * 64 + ((4 * kf + g) ^ (c & 7)) * 8];
                #pragma unroll
                for (int mi = 0; mi < 2; ++mi)
                    o[mi][oj] = __builtin_amdgcn_mfma_f32_16x16x32_bf16(pa[mi], vbf, o[mi][oj], 0, 0, 0);
            }
        }
        __builtin_amdgcn_s_setprio(0);

        __syncthreads();   // drains vmcnt: next tile staged; this tile's reads done
        cur ^= 1;
    }
#undef STAGE

    // ---- finalize: /l, write AO [b, t, h*64+d] bf16
    const int b = bh >> 4, h = bh & 15;
    #pragma unroll
    for (int mi = 0; mi < 2; ++mi)
        #pragma unroll
        for (int j = 0; j < 4; ++j) {
            float inv = 1.0f / l_[mi][j];
            int t = qbase + mi * 16 + g * 4 + j;
            #pragma unroll
            for (int oj = 0; oj < 4; ++oj) {
                int d = oj * 16 + c;
                AOb[(size_t)(b * TT + t) * DM + h * DKK + d] = f2bf(o[mi][oj][j] * inv);
            }
        }
}

// ---------------------------------------------------------------------------
extern "C" void kernel_launch(void* const* d_in, const int* in_sizes, int n_in,
                              void* d_out, int out_size, void* d_ws, size_t ws_size,
                              hipStream_t stream) {
    const float* x  = (const float*)d_in[0];
    const float* wq = (const float*)d_in[1];
    const float* bq = (const float*)d_in[2];
    const float* wk = (const float*)d_in[3];
    const float* bk = (const float*)d_in[4];
    const float* wv = (const float*)d_in[5];
    const float* bv = (const float*)d_in[6];
    const float* wo = (const float*)d_in[7];
    const float* bo = (const float*)d_in[8];

    unsigned short* ws = (unsigned short*)d_ws;
    const size_t NX = (size_t)BB * TT * DM;      // 8388608
    const size_t NW = (size_t)DM * DM;           // 1048576
    unsigned short* xb  = ws;
    unsigned short* wqb = xb + NX;
    unsigned short* wkb = wqb + NW;
    unsigned short* wvb = wkb + NW;
    unsigned short* wob = wvb + NW;
    unsigned short* Qb  = wob + NW;
    unsigned short* Kb  = Qb + NX;
    unsigned short* Vt  = Kb + NX;
    unsigned short* AOb = Vt + NX;

    dim3 blk(256);
    f32_to_bf16<<<dim3((int)(NX / 8 / 256)), blk, 0, stream>>>(x,  xb,  (int)(NX / 8));
    f32_to_bf16<<<dim3((int)(NW / 8 / 256)), blk, 0, stream>>>(wq, wqb, (int)(NW / 8));
    f32_to_bf16<<<dim3((int)(NW / 8 / 256)), blk, 0, stream>>>(wk, wkb, (int)(NW / 8));
    f32_to_bf16<<<dim3((int)(NW / 8 / 256)), blk, 0, stream>>>(wv, wvb, (int)(NW / 8));
    f32_to_bf16<<<dim3((int)(NW / 8 / 256)), blk, 0, stream>>>(wo, wob, (int)(NW / 8));

    qkv_gemm_bf16<<<dim3(64, 24), blk, 0, stream>>>(xb, wqb, wkb, wvb, bq, bk, bv, Qb, Kb, Vt);
    attn_mfma<<<dim3(16, 64), blk, 0, stream>>>(Qb, Kb, Vt, AOb);
    out_gemm_bf16<<<dim3(64, 8), blk, 0, stream>>>(AOb, wob, bo, (float*)d_out);
}